// Round 12
// baseline (309.478 us; speedup 1.0000x reference)
//
#include <hip/hip_runtime.h>
#include <hip/hip_bf16.h>
#include <math.h>

#define Bq 16
#define Lq 2048
#define Hq 256
#define Nst 64
#define LC 128
#define NC 16
#define NL 4
#define BC 256   // Bq*NC
#define GK 256
#define PWS 133  // pw row stride: 133 % 32 = 5, coprime -> bank-clean
#define SZ ((size_t)Bq * Lq * Hq)   // 8388608

typedef __attribute__((ext_vector_type(8))) short short8;
typedef __attribute__((ext_vector_type(4))) float f32x4;
typedef __attribute__((ext_vector_type(4))) unsigned int u32x4;
typedef unsigned short u16;
typedef unsigned int u32;

__device__ __forceinline__ u16 f2b(float x) {
  __hip_bfloat16 b = __float2bfloat16(x);
  u16 u; __builtin_memcpy(&u, &b, 2); return u;
}
__device__ __forceinline__ float b2f(u16 u) {
  u32 t = ((u32)u) << 16; float f; __builtin_memcpy(&f, &t, 4); return f;
}
__device__ __forceinline__ void gload16(const void* g, void* l) {
  __builtin_amdgcn_global_load_lds(
      (const __attribute__((address_space(1))) void*)g,
      (__attribute__((address_space(3))) void*)l, 16, 0, 0);
}

// ---------------- param_k: one block per (layer,h) = lh ----------------
__global__ __launch_bounds__(256) void param_k(
    const float* __restrict__ log_dt, const float* __restrict__ Alog,
    const float* __restrict__ Aim, const float* __restrict__ Cre,
    const float* __restrict__ Cim, const float* __restrict__ Dv,
    u16* __restrict__ Vb, u16* __restrict__ TRb, float* __restrict__ wLc) {
  int lh = blockIdx.x;
  int tid = threadIdx.x;
  __shared__ float pwre[32][PWS], pwim[32][PWS];
  __shared__ float cdre[32], cdim[32];
  __shared__ float kacc[LC];
  __shared__ float kts[LC];
  int ln2 = tid & 31, pg = tid >> 5;   // n-in-half, power segment 0..7
  float dlt = expf(log_dt[lh]);

  for (int pass = 0; pass < 2; ++pass) {
    int n = pass * 32 + ln2;
    int gi = lh * Nst + n;
    float ar = -expf(Alog[gi]);
    float ai = Aim[gi];
    float dr = ar * dlt, di = ai * dlt;
    float er = expf(dr); float sn, cs; sincosf(di, &sn, &cs);
    float wr = er * cs, wi = er * sn;                 // w
    float p0 = (float)(16 * pg);
    float eb = expf(dr * p0); float sb, cb; sincosf(di * p0, &sb, &cb);
    float pr = eb * cb, pi = eb * sb;                 // w^(16*pg)
    #pragma unroll
    for (int s = 0; s < 16; ++s) {
      pwre[ln2][16*pg + s] = pr; pwim[ln2][16*pg + s] = pi;
      float t = pr*wr - pi*wi; pi = fmaf(pr, wi, pi*wr); pr = t;
    }
    if (pg == 7) {                                    // p = 128
      pwre[ln2][128] = pr; pwim[ln2][128] = pi;
      wLc[2*gi] = pr; wLc[2*gi+1] = pi;
    }
    if (pg == 0) {                                    // Cd = C*(w-1)/A
      float nr = wr - 1.f, ni = wi;
      float d2 = ar*ar + ai*ai;
      float qr = (nr*ar + ni*ai) / d2;
      float qi = (ni*ar - nr*ai) / d2;
      float cr = Cre[gi], ci = Cim[gi];
      cdre[ln2] = cr*qr - ci*qi;
      cdim[ln2] = cr*qi + ci*qr;
    }
    __syncthreads();
    if (tid < LC) {
      float s = 0.f;
      #pragma unroll
      for (int k = 0; k < 32; ++k)
        s = fmaf(cdre[k], pwre[k][tid], fmaf(-cdim[k], pwim[k][tid], s));
      if (pass == 0) kacc[tid] = s;
      else kts[tid] = 2.f * (kacc[tid] + s) + ((tid == 0) ? Dv[lh] : 0.f);
    }
    // V fill (x4 = 8 j per lane)
    #pragma unroll
    for (int it = 0; it < 4; ++it) {
      int idx = it * 256 + tid;
      int rl = idx >> 4, g = idx & 15;
      int nl = rl >> 1, im = rl & 1;
      const float* row = im ? pwim[nl] : pwre[nl];
      int pj = 127 - 8 * g;
      u32x4 v;
      #pragma unroll
      for (int e = 0; e < 4; ++e) {
        u32 lo = f2b(row[pj - 2*e]);
        u32 hi = f2b(row[pj - 2*e - 1]);
        v[e] = lo | (hi << 16);
      }
      *(u32x4*)&Vb[((size_t)lh * 128 + 64*pass + rl) * 128 + 8*g] = v;
    }
    // R fill (x4 = 8 rr per lane)
    #pragma unroll
    for (int it = 0; it < 4; ++it) {
      int idx = it * 256 + tid;
      int t = idx >> 3, g = idx & 7;
      u32x4 v;
      #pragma unroll
      for (int k = 0; k < 4; ++k) {
        int nl = 4*g + k;
        float wpr = pwre[nl][t+1], wpi = pwim[nl][t+1];
        float qr = cdre[nl]*wpr - cdim[nl]*wpi;
        float qi = cdre[nl]*wpi + cdim[nl]*wpr;
        v[k] = (u32)f2b(2.f * qr) | ((u32)f2b(-2.f * qi) << 16);
      }
      *(u32x4*)&TRb[((size_t)lh * 128 + t) * 256 + 128 + 64*pass + 8*g] = v;
    }
    __syncthreads();
  }
  // T fill (x4 = 8 j per lane)
  #pragma unroll
  for (int it = 0; it < 8; ++it) {
    int idx = it * 256 + tid;
    int t = idx >> 4, g = idx & 15;
    int j0 = 8 * g;
    u32x4 v;
    #pragma unroll
    for (int e = 0; e < 4; ++e) {
      int j = j0 + 2*e;
      u32 lo = (j     <= t) ? (u32)f2b(kts[t - j])     : 0u;
      u32 hi = (j + 1 <= t) ? (u32)f2b(kts[t - j - 1]) : 0u;
      v[e] = lo | (hi << 16);
    }
    *(u32x4*)&TRb[((size_t)lh * 128 + t) * 256 + j0] = v;
  }
}

// ---------------- W -> bf16 ----------------
__global__ __launch_bounds__(256) void cvtw_k(
    const float* __restrict__ w, __hip_bfloat16* __restrict__ wb, int n) {
  int i = blockIdx.x * 256 + threadIdx.x;
  if (i < n) wb[i] = __float2bfloat16(w[i]);
}

// ---------------- lntr: LN (over H) + transpose -> zt (h, bc, j) bf16 ----------
__global__ __launch_bounds__(512) void lntr_k(
    const float* __restrict__ src, const float* __restrict__ sc,
    const float* __restrict__ bi, u16* __restrict__ zt) {
  int bc = blockIdx.x, jh = blockIdx.y;
  __shared__ u16 Lt[64][Hq + 6];
  int wave = threadIdx.x >> 6, lane = threadIdx.x & 63;
  float4 scv = ((const float4*)sc)[lane];
  float4 biv = ((const float4*)bi)[lane];
  #pragma unroll
  for (int rr = 0; rr < 8; ++rr) {
    int j = wave * 8 + rr;
    size_t row = (size_t)bc * LC + jh * 64 + j;
    const float4 v = ((const float4*)(src + row * Hq))[lane];
    float s  = v.x + v.y + v.z + v.w;
    float s2 = v.x*v.x + v.y*v.y + v.z*v.z + v.w*v.w;
    for (int off = 32; off; off >>= 1) { s += __shfl_down(s, off); s2 += __shfl_down(s2, off); }
    s = __shfl(s, 0); s2 = __shfl(s2, 0);
    float mu = s * (1.f / Hq);
    float var = s2 * (1.f / Hq) - mu * mu;
    float r = rsqrtf(var + 1e-5f);
    u32 w0 = (u32)f2b((v.x - mu) * r * scv.x + biv.x)
           | ((u32)f2b((v.y - mu) * r * scv.y + biv.y) << 16);
    u32 w1 = (u32)f2b((v.z - mu) * r * scv.z + biv.z)
           | ((u32)f2b((v.w - mu) * r * scv.w + biv.w) << 16);
    *(u32*)&Lt[j][4 * lane]     = w0;
    *(u32*)&Lt[j][4 * lane + 2] = w1;
  }
  __syncthreads();
  #pragma unroll
  for (int it = 0; it < 16; ++it) {
    int idx = it * 512 + threadIdx.x;   // h*32 + jl
    int h = idx >> 5, jl = idx & 31;
    u32 lo = Lt[2*jl][h], hi = Lt[2*jl+1][h];
    ((u32*)zt)[((size_t)h * BC + bc) * 64 + jh * 32 + jl] = lo | (hi << 16);
  }
}

// ---------------- s4core: MFMA + in-reg scan + MFMA, double-buffered B ----------
__global__ __launch_bounds__(512) void s4core_k(
    const u16* __restrict__ zt, const u16* __restrict__ Vb,
    const u16* __restrict__ TRb, const float* __restrict__ wLc,
    u16* __restrict__ ytb) {
  int h = blockIdx.y;
  int m0 = blockIdx.x * 128;
  __shared__ u16 As[2][128 * 64];   // zt K-halves; later prev-states
  __shared__ u16 Bs[2][128 * 64];   // double-buffered B tiles
  int tid = threadIdx.x;
  int wid = tid >> 6, lane = tid & 63;
  int cl = lane & 15, kq = lane >> 4;
  int wm = wid & 1, wn = wid >> 1;

  const u16* Ab  = zt  + ((size_t)h * BC + m0) * 128;
  const u16* Vbb = Vb  + (size_t)h * 128 * 128;
  const u16* Tbb = TRb + (size_t)h * 128 * 256;

  #pragma unroll
  for (int half = 0; half < 2; ++half)
    #pragma unroll
    for (int q = 0; q < 2; ++q) {
      int idx = q * 512 + tid;
      int r = idx >> 3, ch = idx & 7;
      gload16(Ab + (size_t)r * 128 + half * 64 + ((ch ^ (r & 7)) << 3),
              (char*)As[half] + (size_t)(q * 512 + (tid & ~63)) * 16);
    }

  auto stageB = [&](const u16* base, int stride, int col0, u16* dst) {
    #pragma unroll
    for (int q = 0; q < 2; ++q) {
      int idx = q * 512 + tid;
      int r = idx >> 3, ch = idx & 7;
      gload16(base + (size_t)r * stride + col0 + ((ch ^ (r & 7)) << 3),
              (char*)dst + (size_t)(q * 512 + (tid & ~63)) * 16);
    }
  };

  f32x4 accS[4][2] = {};
  f32x4 accY[4][2] = {};

  auto mfstep = [&](const u16* Asrc, const u16* Bsrc, f32x4 (*acc)[2]) {
    #pragma unroll
    for (int kk = 0; kk < 2; ++kk) {
      short8 a[4], bf[2];
      #pragma unroll
      for (int mi = 0; mi < 4; ++mi) {
        int m = wm * 64 + mi * 16 + cl;
        int ch = (kk * 4 + kq) ^ (m & 7);
        a[mi] = *(const short8*)(Asrc + m * 64 + ch * 8);
      }
      #pragma unroll
      for (int ni = 0; ni < 2; ++ni) {
        int n = wn * 32 + ni * 16 + cl;
        int ch = (kk * 4 + kq) ^ (n & 7);
        bf[ni] = *(const short8*)(Bsrc + n * 64 + ch * 8);
      }
      #pragma unroll
      for (int mi = 0; mi < 4; ++mi)
        #pragma unroll
        for (int ni = 0; ni < 2; ++ni)
          acc[mi][ni] = __builtin_amdgcn_mfma_f32_16x16x32_bf16(
              a[mi], bf[ni], acc[mi][ni], 0, 0, 0);
    }
  };

  stageB(Vbb, 128, 0, Bs[0]);
  __syncthreads();                                               // S1
  stageB(Vbb, 128, 64, Bs[1]);
  mfstep(As[0], Bs[0], accS);  __syncthreads();                  // S2
  stageB(Tbb, 256, 0, Bs[0]);
  mfstep(As[1], Bs[1], accS);  __syncthreads();                  // S3
  stageB(Tbb, 256, 64, Bs[1]);
  mfstep(As[0], Bs[0], accY);  __syncthreads();                  // S4
  stageB(Tbb, 256, 128, Bs[0]);
  mfstep(As[1], Bs[1], accY);  __syncthreads();                  // S5

  // ---- in-register scan over c; accS becomes prev-state ----
  float sgn = (cl & 1) ? 1.f : -1.f;
  #pragma unroll
  for (int ni = 0; ni < 2; ++ni) {
    int n = (wn * 32 + ni * 16 + cl) >> 1;
    float wr = wLc[2 * (h * Nst + n)];
    float wi = wLc[2 * (h * Nst + n) + 1];
    float swi = sgn * wi;
    #pragma unroll
    for (int mi = 0; mi < 4; ++mi) {
      float carry = 0.f;
      #pragma unroll
      for (int c = 0; c < NC; ++c) {
        float part = __shfl_xor(carry, 1);
        float a_used = accS[mi][ni][c & 3];
        float Sc = fmaf(wr, carry, fmaf(swi, part, a_used));
        if (kq == (c >> 2)) accS[mi][ni][c & 3] = carry;   // prev-state
        carry = __shfl(Sc, ((c >> 2) << 4) + cl);
      }
    }
  }

  #pragma unroll
  for (int mi = 0; mi < 4; ++mi)
    #pragma unroll
    for (int ni = 0; ni < 2; ++ni) {
      int colv = wn * 32 + ni * 16 + cl;
      int half = colv >> 6, cv = colv & 63;
      #pragma unroll
      for (int r = 0; r < 4; ++r) {
        int m = wm * 64 + mi * 16 + kq * 4 + r;
        As[half][m * 64 + (((cv >> 3) ^ (m & 7)) << 3) + (cv & 7)] =
            f2b(accS[mi][ni][r]);
      }
    }
  stageB(Tbb, 256, 192, Bs[1]);
  __syncthreads();                                               // S6
  mfstep(As[0], Bs[0], accY);     // T128 x prev-state lo
  mfstep(As[1], Bs[1], accY);     // T192 x prev-state hi

  #pragma unroll
  for (int mi = 0; mi < 4; ++mi)
    #pragma unroll
    for (int ni = 0; ni < 2; ++ni) {
      int t = wn * 32 + ni * 16 + cl;
      #pragma unroll
      for (int r = 0; r < 4; ++r) {
        int row = m0 + wm * 64 + mi * 16 + kq * 4 + r;
        float x = accY[mi][ni][r];
        float inner = 0.7978845608028654f * fmaf(0.044715f, x*x*x, x);
        float g = 0.5f * x * (1.f + tanhf(inner));
        ytb[((size_t)h * BC + row) * LC + t] = f2b(g);
      }
    }
}

// ---------------- gemm: A from ytb via in-LDS transpose + bias/GLU/residual ----
// Block (bc, ot): rows bl = bc*128 + t. Per kt-half (h in [k0,k0+64)):
//   Lt32[hh][tp] = ytb t-pair u32 of row h=k0+hh (coalesced global reads)
//   As packed from Lt32 in the verified swizzled layout:
//     As[64m + 8*((k>>3)^(m&7)) + (k&7)] = elem(m=t, k=hh)   [bit-identical]
__global__ __launch_bounds__(256) void gemm_k(
    const u16* __restrict__ ytb, const __hip_bfloat16* __restrict__ Wb,
    const float* __restrict__ bout, const float* __restrict__ rsrc,
    float* __restrict__ hb) {
  __shared__ u32 Lt32[64 * 65];             // [hh][tp], stride 65
  __shared__ __hip_bfloat16 As[128 * 64];
  __shared__ __hip_bfloat16 Bs[128 * 64];
  int tid = threadIdx.x;
  int bc = blockIdx.x;
  int m0 = bc * 128;
  int ot = blockIdx.y;
  int wid = tid >> 6, lane = tid & 63;
  int cl = lane & 15, kq = lane >> 4;
  f32x4 acc[2][8] = {};
  for (int kt = 0; kt < GK / 64; ++kt) {
    int k0 = kt * 64;
    // B staging (async)
    #pragma unroll
    for (int q = 0; q < 4; ++q) {
      int idx = q * 256 + tid;
      int r = idx >> 3, ch = idx & 7;
      int wrow = ot * 64 + r + ((r >= 64) ? 192 : 0);
      const __hip_bfloat16* sB =
          Wb + (size_t)wrow * GK + k0 + ((ch ^ (r & 7)) << 3);
      gload16(sB, (char*)Bs + (size_t)(q * 256 + (tid & ~63)) * 16);
    }
    // Lt32 fill: row hh of ytb (h=k0+hh), 64 u32 t-pairs, coalesced
    #pragma unroll
    for (int i2 = 0; i2 < 16; ++i2) {
      int idx = i2 * 256 + tid;
      int hh = idx >> 6, tp = idx & 63;
      Lt32[hh * 65 + tp] =
          ((const u32*)ytb)[((size_t)(k0 + hh) * BC + bc) * 64 + tp];
    }
    __syncthreads();
    // As write: element (m=t, k=2hl / 2hl+1) packed u32, swizzled layout
    #pragma unroll
    for (int i2 = 0; i2 < 16; ++i2) {
      int idx = i2 * 256 + tid;
      int m = idx >> 5, hl = idx & 31;
      u32 v0 = Lt32[(2 * hl) * 65 + (m >> 1)];
      u32 v1 = Lt32[(2 * hl + 1) * 65 + (m >> 1)];
      u32 lo = (m & 1) ? (v0 >> 16) : (v0 & 0xffffu);
      u32 hi = (m & 1) ? (v1 >> 16) : (v1 & 0xffffu);
      ((u32*)As)[m * 32 + (((hl >> 2) ^ (m & 7)) << 2) + (hl & 3)] =
          lo | (hi << 16);
    }
    __syncthreads();
    #pragma unroll
    for (int kk = 0; kk < 2; ++kk) {
      short8 a[2], bfr[8];
      #pragma unroll
      for (int mi = 0; mi < 2; ++mi) {
        int m = wid * 32 + mi * 16 + cl;
        int ch = (kk * 4 + kq) ^ (m & 7);
        a[mi] = *(const short8*)(As + m * 64 + ch * 8);
      }
      #pragma unroll
      for (int ni = 0; ni < 8; ++ni) {
        int n = ni * 16 + cl;
        int ch = (kk * 4 + kq) ^ (n & 7);
        bfr[ni] = *(const short8*)(Bs + n * 64 + ch * 8);
      }
      #pragma unroll
      for (int mi = 0; mi < 2; ++mi)
        #pragma unroll
        for (int ni = 0; ni < 8; ++ni)
          acc[mi][ni] = __builtin_amdgcn_mfma_f32_16x16x32_bf16(
              a[mi], bfr[ni], acc[mi][ni], 0, 0, 0);
    }
    __syncthreads();
  }
  #pragma unroll
  for (int mi = 0; mi < 2; ++mi) {
    #pragma unroll
    for (int ni = 0; ni < 4; ++ni) {
      int o1 = ot * 64 + ni * 16 + cl;
      float b1 = bout[o1], b2 = bout[o1 + 256];
      #pragma unroll
      for (int r = 0; r < 4; ++r) {
        int row = m0 + wid * 32 + mi * 16 + kq * 4 + r;
        float z1 = acc[mi][ni][r] + b1;
        float z2 = acc[mi][ni + 4][r] + b2;
        float g = z1 / (1.f + expf(-z2));
        size_t idx = (size_t)row * Hq + o1;
        hb[idx] = rsrc[idx] + g;
      }
    }
  }
}

extern "C" void kernel_launch(void* const* d_in, const int* in_sizes, int n_in,
                              void* d_out, int out_size, void* d_ws, size_t ws_size,
                              hipStream_t stream) {
  (void)in_sizes; (void)n_in; (void)out_size; (void)ws_size;
  const float* x      = (const float*)d_in[0];
  const float* log_dt = (const float*)d_in[1];
  const float* Alog   = (const float*)d_in[2];
  const float* Aim    = (const float*)d_in[3];
  const float* Cre    = (const float*)d_in[4];
  const float* Cim    = (const float*)d_in[5];
  const float* Dv     = (const float*)d_in[6];
  const float* Wout   = (const float*)d_in[7];
  const float* bout   = (const float*)d_in[8];
  const float* lns    = (const float*)d_in[9];
  const float* lnb    = (const float*)d_in[10];

  float* hb = (float*)d_out;
  float* p  = (float*)d_ws;
  u16* zt  = (u16*)p; p += SZ/2;               // (h, bc, j) bf16
  u16* ytb = (u16*)p; p += SZ/2;               // (h, bc, t) bf16
  u16* Vb  = (u16*)p; p += SZ;                 // NL*Hq*128*128 u16
  u16* TRb = (u16*)p; p += 2*SZ;               // NL*Hq*128*256 u16
  u16* Wb  = (u16*)p; p += (NL*2*Hq*Hq)/2;     // bf16 weights, all layers
  float* wLc = p;  p += NL*2*Hq*Nst;

  cvtw_k<<<(NL*2*Hq*Hq)/256, 256, 0, stream>>>(Wout, (__hip_bfloat16*)Wb, NL*2*Hq*Hq);
  param_k<<<NL*Hq, 256, 0, stream>>>(log_dt, Alog, Aim, Cre, Cim, Dv, Vb, TRb, wLc);

  for (int i = 0; i < NL; ++i) {
    const float* src = (i == 0) ? x : hb;
    lntr_k<<<dim3(BC, 2), 512, 0, stream>>>(src, lns + i*Hq, lnb + i*Hq, zt);
    s4core_k<<<dim3(2, Hq), 512, 0, stream>>>(
        zt, Vb + (size_t)i * Hq * 128 * 128, TRb + (size_t)i * Hq * 128 * 256,
        wLc + (size_t)i * 2 * Hq * Nst, ytb);
    gemm_k<<<dim3(BC, 4), 256, 0, stream>>>(
        ytb, (const __hip_bfloat16*)(Wb + (size_t)i * 2 * Hq * Hq),
        bout + (size_t)i*2*Hq, src, hb);
  }
}

// Round 13
// 308.501 us; speedup vs baseline: 1.0032x; 1.0032x over previous
//
#include <hip/hip_runtime.h>
#include <hip/hip_bf16.h>
#include <math.h>

#define Bq 16
#define Lq 2048
#define Hq 256
#define Nst 64
#define LC 128
#define NC 16
#define NL 4
#define BC 256   // Bq*NC
#define GK 256
#define PWS 133  // pw row stride: 133 % 32 = 5, coprime -> bank-clean
#define SZ ((size_t)Bq * Lq * Hq)   // 8388608

typedef __attribute__((ext_vector_type(8))) short short8;
typedef __attribute__((ext_vector_type(4))) float f32x4;
typedef __attribute__((ext_vector_type(4))) unsigned int u32x4;
typedef unsigned short u16;
typedef unsigned int u32;

__device__ __forceinline__ u16 f2b(float x) {
  __hip_bfloat16 b = __float2bfloat16(x);
  u16 u; __builtin_memcpy(&u, &b, 2); return u;
}
__device__ __forceinline__ float b2f(u16 u) {
  u32 t = ((u32)u) << 16; float f; __builtin_memcpy(&f, &t, 4); return f;
}
__device__ __forceinline__ void gload16(const void* g, void* l) {
  __builtin_amdgcn_global_load_lds(
      (const __attribute__((address_space(1))) void*)g,
      (__attribute__((address_space(3))) void*)l, 16, 0, 0);
}

// ---------------- param_k: one block per (layer,h) = lh ----------------
__global__ __launch_bounds__(256) void param_k(
    const float* __restrict__ log_dt, const float* __restrict__ Alog,
    const float* __restrict__ Aim, const float* __restrict__ Cre,
    const float* __restrict__ Cim, const float* __restrict__ Dv,
    u16* __restrict__ Vb, u16* __restrict__ TRb, float* __restrict__ wLc) {
  int lh = blockIdx.x;
  int tid = threadIdx.x;
  __shared__ float pwre[32][PWS], pwim[32][PWS];
  __shared__ float cdre[32], cdim[32];
  __shared__ float kacc[LC];
  __shared__ float kts[LC];
  int ln2 = tid & 31, pg = tid >> 5;   // n-in-half, power segment 0..7
  float dlt = expf(log_dt[lh]);

  for (int pass = 0; pass < 2; ++pass) {
    int n = pass * 32 + ln2;
    int gi = lh * Nst + n;
    float ar = -expf(Alog[gi]);
    float ai = Aim[gi];
    float dr = ar * dlt, di = ai * dlt;
    float er = expf(dr); float sn, cs; sincosf(di, &sn, &cs);
    float wr = er * cs, wi = er * sn;                 // w
    float p0 = (float)(16 * pg);
    float eb = expf(dr * p0); float sb, cb; sincosf(di * p0, &sb, &cb);
    float pr = eb * cb, pi = eb * sb;                 // w^(16*pg)
    #pragma unroll
    for (int s = 0; s < 16; ++s) {
      pwre[ln2][16*pg + s] = pr; pwim[ln2][16*pg + s] = pi;
      float t = pr*wr - pi*wi; pi = fmaf(pr, wi, pi*wr); pr = t;
    }
    if (pg == 7) {                                    // p = 128
      pwre[ln2][128] = pr; pwim[ln2][128] = pi;
      wLc[2*gi] = pr; wLc[2*gi+1] = pi;
    }
    if (pg == 0) {                                    // Cd = C*(w-1)/A
      float nr = wr - 1.f, ni = wi;
      float d2 = ar*ar + ai*ai;
      float qr = (nr*ar + ni*ai) / d2;
      float qi = (ni*ar - nr*ai) / d2;
      float cr = Cre[gi], ci = Cim[gi];
      cdre[ln2] = cr*qr - ci*qi;
      cdim[ln2] = cr*qi + ci*qr;
    }
    __syncthreads();
    if (tid < LC) {
      float s = 0.f;
      #pragma unroll
      for (int k = 0; k < 32; ++k)
        s = fmaf(cdre[k], pwre[k][tid], fmaf(-cdim[k], pwim[k][tid], s));
      if (pass == 0) kacc[tid] = s;
      else kts[tid] = 2.f * (kacc[tid] + s) + ((tid == 0) ? Dv[lh] : 0.f);
    }
    // V fill (x4 = 8 j per lane)
    #pragma unroll
    for (int it = 0; it < 4; ++it) {
      int idx = it * 256 + tid;
      int rl = idx >> 4, g = idx & 15;
      int nl = rl >> 1, im = rl & 1;
      const float* row = im ? pwim[nl] : pwre[nl];
      int pj = 127 - 8 * g;
      u32x4 v;
      #pragma unroll
      for (int e = 0; e < 4; ++e) {
        u32 lo = f2b(row[pj - 2*e]);
        u32 hi = f2b(row[pj - 2*e - 1]);
        v[e] = lo | (hi << 16);
      }
      *(u32x4*)&Vb[((size_t)lh * 128 + 64*pass + rl) * 128 + 8*g] = v;
    }
    // R fill (x4 = 8 rr per lane)
    #pragma unroll
    for (int it = 0; it < 4; ++it) {
      int idx = it * 256 + tid;
      int t = idx >> 3, g = idx & 7;
      u32x4 v;
      #pragma unroll
      for (int k = 0; k < 4; ++k) {
        int nl = 4*g + k;
        float wpr = pwre[nl][t+1], wpi = pwim[nl][t+1];
        float qr = cdre[nl]*wpr - cdim[nl]*wpi;
        float qi = cdre[nl]*wpi + cdim[nl]*wpr;
        v[k] = (u32)f2b(2.f * qr) | ((u32)f2b(-2.f * qi) << 16);
      }
      *(u32x4*)&TRb[((size_t)lh * 128 + t) * 256 + 128 + 64*pass + 8*g] = v;
    }
    __syncthreads();
  }
  // T fill (x4 = 8 j per lane)
  #pragma unroll
  for (int it = 0; it < 8; ++it) {
    int idx = it * 256 + tid;
    int t = idx >> 4, g = idx & 15;
    int j0 = 8 * g;
    u32x4 v;
    #pragma unroll
    for (int e = 0; e < 4; ++e) {
      int j = j0 + 2*e;
      u32 lo = (j     <= t) ? (u32)f2b(kts[t - j])     : 0u;
      u32 hi = (j + 1 <= t) ? (u32)f2b(kts[t - j - 1]) : 0u;
      v[e] = lo | (hi << 16);
    }
    *(u32x4*)&TRb[((size_t)lh * 128 + t) * 256 + j0] = v;
  }
}

// ---------------- W -> bf16 ----------------
__global__ __launch_bounds__(256) void cvtw_k(
    const float* __restrict__ w, __hip_bfloat16* __restrict__ wb, int n) {
  int i = blockIdx.x * 256 + threadIdx.x;
  if (i < n) wb[i] = __float2bfloat16(w[i]);
}

// ---------------- lntr: LN (over H) + transpose -> zt (h, bc, j) bf16 ----------
// SRCF32: src is f32 (layer 0 input x); else bf16 residual stream hbf.
template <bool SRCF32>
__global__ __launch_bounds__(512) void lntr_k(
    const void* __restrict__ srcv, const float* __restrict__ sc,
    const float* __restrict__ bi, u16* __restrict__ zt) {
  int bc = blockIdx.x, jh = blockIdx.y;
  __shared__ u16 Lt[64][Hq + 6];
  int wave = threadIdx.x >> 6, lane = threadIdx.x & 63;
  float4 scv = ((const float4*)sc)[lane];
  float4 biv = ((const float4*)bi)[lane];
  #pragma unroll
  for (int rr = 0; rr < 8; ++rr) {
    int j = wave * 8 + rr;
    size_t row = (size_t)bc * LC + jh * 64 + j;
    float4 v;
    if constexpr (SRCF32) {
      v = ((const float4*)((const float*)srcv + row * Hq))[lane];
    } else {
      ushort4 u = ((const ushort4*)((const u16*)srcv + row * Hq))[lane];
      v.x = b2f(u.x); v.y = b2f(u.y); v.z = b2f(u.z); v.w = b2f(u.w);
    }
    float s  = v.x + v.y + v.z + v.w;
    float s2 = v.x*v.x + v.y*v.y + v.z*v.z + v.w*v.w;
    for (int off = 32; off; off >>= 1) { s += __shfl_down(s, off); s2 += __shfl_down(s2, off); }
    s = __shfl(s, 0); s2 = __shfl(s2, 0);
    float mu = s * (1.f / Hq);
    float var = s2 * (1.f / Hq) - mu * mu;
    float r = rsqrtf(var + 1e-5f);
    u32 w0 = (u32)f2b((v.x - mu) * r * scv.x + biv.x)
           | ((u32)f2b((v.y - mu) * r * scv.y + biv.y) << 16);
    u32 w1 = (u32)f2b((v.z - mu) * r * scv.z + biv.z)
           | ((u32)f2b((v.w - mu) * r * scv.w + biv.w) << 16);
    *(u32*)&Lt[j][4 * lane]     = w0;
    *(u32*)&Lt[j][4 * lane + 2] = w1;
  }
  __syncthreads();
  #pragma unroll
  for (int it = 0; it < 16; ++it) {
    int idx = it * 512 + threadIdx.x;   // h*32 + jl
    int h = idx >> 5, jl = idx & 31;
    u32 lo = Lt[2*jl][h], hi = Lt[2*jl+1][h];
    ((u32*)zt)[((size_t)h * BC + bc) * 64 + jh * 32 + jl] = lo | (hi << 16);
  }
}

// ---------------- s4core: MFMA + in-reg scan + MFMA, double-buffered B ----------
__global__ __launch_bounds__(512) void s4core_k(
    const u16* __restrict__ zt, const u16* __restrict__ Vb,
    const u16* __restrict__ TRb, const float* __restrict__ wLc,
    u16* __restrict__ ytb) {
  int h = blockIdx.y;
  int m0 = blockIdx.x * 128;
  __shared__ u16 As[2][128 * 64];   // zt K-halves; later prev-states
  __shared__ u16 Bs[2][128 * 64];   // double-buffered B tiles
  int tid = threadIdx.x;
  int wid = tid >> 6, lane = tid & 63;
  int cl = lane & 15, kq = lane >> 4;
  int wm = wid & 1, wn = wid >> 1;

  const u16* Ab  = zt  + ((size_t)h * BC + m0) * 128;
  const u16* Vbb = Vb  + (size_t)h * 128 * 128;
  const u16* Tbb = TRb + (size_t)h * 128 * 256;

  #pragma unroll
  for (int half = 0; half < 2; ++half)
    #pragma unroll
    for (int q = 0; q < 2; ++q) {
      int idx = q * 512 + tid;
      int r = idx >> 3, ch = idx & 7;
      gload16(Ab + (size_t)r * 128 + half * 64 + ((ch ^ (r & 7)) << 3),
              (char*)As[half] + (size_t)(q * 512 + (tid & ~63)) * 16);
    }

  auto stageB = [&](const u16* base, int stride, int col0, u16* dst) {
    #pragma unroll
    for (int q = 0; q < 2; ++q) {
      int idx = q * 512 + tid;
      int r = idx >> 3, ch = idx & 7;
      gload16(base + (size_t)r * stride + col0 + ((ch ^ (r & 7)) << 3),
              (char*)dst + (size_t)(q * 512 + (tid & ~63)) * 16);
    }
  };

  f32x4 accS[4][2] = {};
  f32x4 accY[4][2] = {};

  auto mfstep = [&](const u16* Asrc, const u16* Bsrc, f32x4 (*acc)[2]) {
    #pragma unroll
    for (int kk = 0; kk < 2; ++kk) {
      short8 a[4], bf[2];
      #pragma unroll
      for (int mi = 0; mi < 4; ++mi) {
        int m = wm * 64 + mi * 16 + cl;
        int ch = (kk * 4 + kq) ^ (m & 7);
        a[mi] = *(const short8*)(Asrc + m * 64 + ch * 8);
      }
      #pragma unroll
      for (int ni = 0; ni < 2; ++ni) {
        int n = wn * 32 + ni * 16 + cl;
        int ch = (kk * 4 + kq) ^ (n & 7);
        bf[ni] = *(const short8*)(Bsrc + n * 64 + ch * 8);
      }
      #pragma unroll
      for (int mi = 0; mi < 4; ++mi)
        #pragma unroll
        for (int ni = 0; ni < 2; ++ni)
          acc[mi][ni] = __builtin_amdgcn_mfma_f32_16x16x32_bf16(
              a[mi], bf[ni], acc[mi][ni], 0, 0, 0);
    }
  };

  stageB(Vbb, 128, 0, Bs[0]);
  __syncthreads();                                               // S1
  stageB(Vbb, 128, 64, Bs[1]);
  mfstep(As[0], Bs[0], accS);  __syncthreads();                  // S2
  stageB(Tbb, 256, 0, Bs[0]);
  mfstep(As[1], Bs[1], accS);  __syncthreads();                  // S3
  stageB(Tbb, 256, 64, Bs[1]);
  mfstep(As[0], Bs[0], accY);  __syncthreads();                  // S4
  stageB(Tbb, 256, 128, Bs[0]);
  mfstep(As[1], Bs[1], accY);  __syncthreads();                  // S5

  // ---- in-register scan over c; accS becomes prev-state ----
  float sgn = (cl & 1) ? 1.f : -1.f;
  #pragma unroll
  for (int ni = 0; ni < 2; ++ni) {
    int n = (wn * 32 + ni * 16 + cl) >> 1;
    float wr = wLc[2 * (h * Nst + n)];
    float wi = wLc[2 * (h * Nst + n) + 1];
    float swi = sgn * wi;
    #pragma unroll
    for (int mi = 0; mi < 4; ++mi) {
      float carry = 0.f;
      #pragma unroll
      for (int c = 0; c < NC; ++c) {
        float part = __shfl_xor(carry, 1);
        float a_used = accS[mi][ni][c & 3];
        float Sc = fmaf(wr, carry, fmaf(swi, part, a_used));
        if (kq == (c >> 2)) accS[mi][ni][c & 3] = carry;   // prev-state
        carry = __shfl(Sc, ((c >> 2) << 4) + cl);
      }
    }
  }

  #pragma unroll
  for (int mi = 0; mi < 4; ++mi)
    #pragma unroll
    for (int ni = 0; ni < 2; ++ni) {
      int colv = wn * 32 + ni * 16 + cl;
      int half = colv >> 6, cv = colv & 63;
      #pragma unroll
      for (int r = 0; r < 4; ++r) {
        int m = wm * 64 + mi * 16 + kq * 4 + r;
        As[half][m * 64 + (((cv >> 3) ^ (m & 7)) << 3) + (cv & 7)] =
            f2b(accS[mi][ni][r]);
      }
    }
  stageB(Tbb, 256, 192, Bs[1]);
  __syncthreads();                                               // S6
  mfstep(As[0], Bs[0], accY);     // T128 x prev-state lo
  mfstep(As[1], Bs[1], accY);     // T192 x prev-state hi

  #pragma unroll
  for (int mi = 0; mi < 4; ++mi)
    #pragma unroll
    for (int ni = 0; ni < 2; ++ni) {
      int t = wn * 32 + ni * 16 + cl;
      #pragma unroll
      for (int r = 0; r < 4; ++r) {
        int row = m0 + wm * 64 + mi * 16 + kq * 4 + r;
        float x = accY[mi][ni][r];
        float inner = 0.7978845608028654f * fmaf(0.044715f, x*x*x, x);
        float g = 0.5f * x * (1.f + tanhf(inner));
        ytb[((size_t)h * BC + row) * LC + t] = f2b(g);
      }
    }
}

// ---------------- gemm: A from ytb via in-LDS transpose + bias/GLU/residual ----
// SRCF32: residual source is f32 (layer 0: x); else bf16 hbf.
// DSTF32: write f32 (layer 3: d_out); else bf16 hbf.
template <bool SRCF32, bool DSTF32>
__global__ __launch_bounds__(256) void gemm_k(
    const u16* __restrict__ ytb, const __hip_bfloat16* __restrict__ Wb,
    const float* __restrict__ bout, const void* __restrict__ rsrcv,
    void* __restrict__ dstv) {
  __shared__ u32 Lt32[64 * 65];             // [hh][tp], stride 65
  __shared__ __hip_bfloat16 As[128 * 64];
  __shared__ __hip_bfloat16 Bs[128 * 64];
  int tid = threadIdx.x;
  int bc = blockIdx.x;
  int m0 = bc * 128;
  int ot = blockIdx.y;
  int wid = tid >> 6, lane = tid & 63;
  int cl = lane & 15, kq = lane >> 4;
  f32x4 acc[2][8] = {};
  for (int kt = 0; kt < GK / 64; ++kt) {
    int k0 = kt * 64;
    // B staging (async)
    #pragma unroll
    for (int q = 0; q < 4; ++q) {
      int idx = q * 256 + tid;
      int r = idx >> 3, ch = idx & 7;
      int wrow = ot * 64 + r + ((r >= 64) ? 192 : 0);
      const __hip_bfloat16* sB =
          Wb + (size_t)wrow * GK + k0 + ((ch ^ (r & 7)) << 3);
      gload16(sB, (char*)Bs + (size_t)(q * 256 + (tid & ~63)) * 16);
    }
    // Lt32 fill: row hh of ytb (h=k0+hh), 64 u32 t-pairs, coalesced
    #pragma unroll
    for (int i2 = 0; i2 < 16; ++i2) {
      int idx = i2 * 256 + tid;
      int hh = idx >> 6, tp = idx & 63;
      Lt32[hh * 65 + tp] =
          ((const u32*)ytb)[((size_t)(k0 + hh) * BC + bc) * 64 + tp];
    }
    __syncthreads();
    // As write: element (m=t, k=2hl / 2hl+1) packed u32, swizzled layout
    #pragma unroll
    for (int i2 = 0; i2 < 16; ++i2) {
      int idx = i2 * 256 + tid;
      int m = idx >> 5, hl = idx & 31;
      u32 v0 = Lt32[(2 * hl) * 65 + (m >> 1)];
      u32 v1 = Lt32[(2 * hl + 1) * 65 + (m >> 1)];
      u32 lo = (m & 1) ? (v0 >> 16) : (v0 & 0xffffu);
      u32 hi = (m & 1) ? (v1 >> 16) : (v1 & 0xffffu);
      ((u32*)As)[m * 32 + (((hl >> 2) ^ (m & 7)) << 2) + (hl & 3)] =
          lo | (hi << 16);
    }
    __syncthreads();
    #pragma unroll
    for (int kk = 0; kk < 2; ++kk) {
      short8 a[2], bfr[8];
      #pragma unroll
      for (int mi = 0; mi < 2; ++mi) {
        int m = wid * 32 + mi * 16 + cl;
        int ch = (kk * 4 + kq) ^ (m & 7);
        a[mi] = *(const short8*)(As + m * 64 + ch * 8);
      }
      #pragma unroll
      for (int ni = 0; ni < 8; ++ni) {
        int n = ni * 16 + cl;
        int ch = (kk * 4 + kq) ^ (n & 7);
        bfr[ni] = *(const short8*)(Bs + n * 64 + ch * 8);
      }
      #pragma unroll
      for (int mi = 0; mi < 2; ++mi)
        #pragma unroll
        for (int ni = 0; ni < 8; ++ni)
          acc[mi][ni] = __builtin_amdgcn_mfma_f32_16x16x32_bf16(
              a[mi], bfr[ni], acc[mi][ni], 0, 0, 0);
    }
    __syncthreads();
  }
  #pragma unroll
  for (int mi = 0; mi < 2; ++mi) {
    #pragma unroll
    for (int ni = 0; ni < 4; ++ni) {
      int o1 = ot * 64 + ni * 16 + cl;
      float b1 = bout[o1], b2 = bout[o1 + 256];
      #pragma unroll
      for (int r = 0; r < 4; ++r) {
        int row = m0 + wid * 32 + mi * 16 + kq * 4 + r;
        float z1 = acc[mi][ni][r] + b1;
        float z2 = acc[mi][ni + 4][r] + b2;
        float g = z1 / (1.f + expf(-z2));
        size_t idx = (size_t)row * Hq + o1;
        float rv;
        if constexpr (SRCF32) rv = ((const float*)rsrcv)[idx];
        else                  rv = b2f(((const u16*)rsrcv)[idx]);
        float o = rv + g;
        if constexpr (DSTF32) ((float*)dstv)[idx] = o;
        else                  ((u16*)dstv)[idx] = f2b(o);
      }
    }
  }
}

extern "C" void kernel_launch(void* const* d_in, const int* in_sizes, int n_in,
                              void* d_out, int out_size, void* d_ws, size_t ws_size,
                              hipStream_t stream) {
  (void)in_sizes; (void)n_in; (void)out_size; (void)ws_size;
  const float* x      = (const float*)d_in[0];
  const float* log_dt = (const float*)d_in[1];
  const float* Alog   = (const float*)d_in[2];
  const float* Aim    = (const float*)d_in[3];
  const float* Cre    = (const float*)d_in[4];
  const float* Cim    = (const float*)d_in[5];
  const float* Dv     = (const float*)d_in[6];
  const float* Wout   = (const float*)d_in[7];
  const float* bout   = (const float*)d_in[8];
  const float* lns    = (const float*)d_in[9];
  const float* lnb    = (const float*)d_in[10];

  float* hb = (float*)d_out;
  float* p  = (float*)d_ws;
  u16* zt  = (u16*)p; p += SZ/2;               // (h, bc, j) bf16
  u16* ytb = (u16*)p; p += SZ/2;               // (h, bc, t) bf16
  u16* hbf = (u16*)p; p += SZ/2;               // bf16 residual stream
  u16* Vb  = (u16*)p; p += SZ;                 // NL*Hq*128*128 u16
  u16* TRb = (u16*)p; p += 2*SZ;               // NL*Hq*128*256 u16
  u16* Wb  = (u16*)p; p += (NL*2*Hq*Hq)/2;     // bf16 weights, all layers
  float* wLc = p;  p += NL*2*Hq*Nst;

  cvtw_k<<<(NL*2*Hq*Hq)/256, 256, 0, stream>>>(Wout, (__hip_bfloat16*)Wb, NL*2*Hq*Hq);
  param_k<<<NL*Hq, 256, 0, stream>>>(log_dt, Alog, Aim, Cre, Cim, Dv, Vb, TRb, wLc);

  for (int i = 0; i < NL; ++i) {
    // lntr: src = x (f32) for layer 0, else hbf (bf16)
    if (i == 0)
      lntr_k<true><<<dim3(BC, 2), 512, 0, stream>>>(x, lns + i*Hq, lnb + i*Hq, zt);
    else
      lntr_k<false><<<dim3(BC, 2), 512, 0, stream>>>(hbf, lns + i*Hq, lnb + i*Hq, zt);

    s4core_k<<<dim3(2, Hq), 512, 0, stream>>>(
        zt, Vb + (size_t)i * Hq * 128 * 128, TRb + (size_t)i * Hq * 128 * 256,
        wLc + (size_t)i * 2 * Hq * Nst, ytb);

    const __hip_bfloat16* Wbi = (const __hip_bfloat16*)(Wb + (size_t)i * 2 * Hq * Hq);
    const float* bo = bout + (size_t)i * 2 * Hq;
    if (i == 0)
      gemm_k<true, false><<<dim3(BC, 4), 256, 0, stream>>>(ytb, Wbi, bo, x, hbf);
    else if (i == NL - 1)
      gemm_k<false, true><<<dim3(BC, 4), 256, 0, stream>>>(ytb, Wbi, bo, hbf, hb);
    else
      gemm_k<false, false><<<dim3(BC, 4), 256, 0, stream>>>(ytb, Wbi, bo, hbf, hbf);
  }
}

// Round 15
// 308.326 us; speedup vs baseline: 1.0037x; 1.0006x over previous
//
#include <hip/hip_runtime.h>
#include <hip/hip_bf16.h>
#include <math.h>

#define Bq 16
#define Lq 2048
#define Hq 256
#define Nst 64
#define LC 128
#define NC 16
#define NL 4
#define BC 256   // Bq*NC
#define GK 256
#define PWS 133  // pw row stride: 133 % 32 = 5, coprime -> bank-clean
#define SZ ((size_t)Bq * Lq * Hq)   // 8388608

typedef __attribute__((ext_vector_type(8))) short short8;
typedef __attribute__((ext_vector_type(4))) float f32x4;
typedef __attribute__((ext_vector_type(4))) unsigned int u32x4;
typedef unsigned short u16;
typedef unsigned int u32;

__device__ __forceinline__ u16 f2b(float x) {
  __hip_bfloat16 b = __float2bfloat16(x);
  u16 u; __builtin_memcpy(&u, &b, 2); return u;
}
__device__ __forceinline__ float b2f(u16 u) {
  u32 t = ((u32)u) << 16; float f; __builtin_memcpy(&f, &t, 4); return f;
}
__device__ __forceinline__ void gload16(const void* g, void* l) {
  __builtin_amdgcn_global_load_lds(
      (const __attribute__((address_space(1))) void*)g,
      (__attribute__((address_space(3))) void*)l, 16, 0, 0);
}

// ---------------- param_k: one block per (layer,h) = lh ----------------
__global__ __launch_bounds__(256) void param_k(
    const float* __restrict__ log_dt, const float* __restrict__ Alog,
    const float* __restrict__ Aim, const float* __restrict__ Cre,
    const float* __restrict__ Cim, const float* __restrict__ Dv,
    u16* __restrict__ Vb, u16* __restrict__ TRb, float* __restrict__ wLc) {
  int lh = blockIdx.x;
  int tid = threadIdx.x;
  __shared__ float pwre[32][PWS], pwim[32][PWS];
  __shared__ float cdre[32], cdim[32];
  __shared__ float kacc[LC];
  __shared__ float kts[LC];
  int ln2 = tid & 31, pg = tid >> 5;   // n-in-half, power segment 0..7
  float dlt = expf(log_dt[lh]);

  for (int pass = 0; pass < 2; ++pass) {
    int n = pass * 32 + ln2;
    int gi = lh * Nst + n;
    float ar = -expf(Alog[gi]);
    float ai = Aim[gi];
    float dr = ar * dlt, di = ai * dlt;
    float er = expf(dr); float sn, cs; sincosf(di, &sn, &cs);
    float wr = er * cs, wi = er * sn;                 // w
    float p0 = (float)(16 * pg);
    float eb = expf(dr * p0); float sb, cb; sincosf(di * p0, &sb, &cb);
    float pr = eb * cb, pi = eb * sb;                 // w^(16*pg)
    #pragma unroll
    for (int s = 0; s < 16; ++s) {
      pwre[ln2][16*pg + s] = pr; pwim[ln2][16*pg + s] = pi;
      float t = pr*wr - pi*wi; pi = fmaf(pr, wi, pi*wr); pr = t;
    }
    if (pg == 7) {                                    // p = 128
      pwre[ln2][128] = pr; pwim[ln2][128] = pi;
      wLc[2*gi] = pr; wLc[2*gi+1] = pi;
    }
    if (pg == 0) {                                    // Cd = C*(w-1)/A
      float nr = wr - 1.f, ni = wi;
      float d2 = ar*ar + ai*ai;
      float qr = (nr*ar + ni*ai) / d2;
      float qi = (ni*ar - nr*ai) / d2;
      float cr = Cre[gi], ci = Cim[gi];
      cdre[ln2] = cr*qr - ci*qi;
      cdim[ln2] = cr*qi + ci*qr;
    }
    __syncthreads();
    if (tid < LC) {
      float s = 0.f;
      #pragma unroll
      for (int k = 0; k < 32; ++k)
        s = fmaf(cdre[k], pwre[k][tid], fmaf(-cdim[k], pwim[k][tid], s));
      if (pass == 0) kacc[tid] = s;
      else kts[tid] = 2.f * (kacc[tid] + s) + ((tid == 0) ? Dv[lh] : 0.f);
    }
    // V fill (x4 = 8 j per lane)
    #pragma unroll
    for (int it = 0; it < 4; ++it) {
      int idx = it * 256 + tid;
      int rl = idx >> 4, g = idx & 15;
      int nl = rl >> 1, im = rl & 1;
      const float* row = im ? pwim[nl] : pwre[nl];
      int pj = 127 - 8 * g;
      u32x4 v;
      #pragma unroll
      for (int e = 0; e < 4; ++e) {
        u32 lo = f2b(row[pj - 2*e]);
        u32 hi = f2b(row[pj - 2*e - 1]);
        v[e] = lo | (hi << 16);
      }
      *(u32x4*)&Vb[((size_t)lh * 128 + 64*pass + rl) * 128 + 8*g] = v;
    }
    // R fill (x4 = 8 rr per lane)
    #pragma unroll
    for (int it = 0; it < 4; ++it) {
      int idx = it * 256 + tid;
      int t = idx >> 3, g = idx & 7;
      u32x4 v;
      #pragma unroll
      for (int k = 0; k < 4; ++k) {
        int nl = 4*g + k;
        float wpr = pwre[nl][t+1], wpi = pwim[nl][t+1];
        float qr = cdre[nl]*wpr - cdim[nl]*wpi;
        float qi = cdre[nl]*wpi + cdim[nl]*wpr;
        v[k] = (u32)f2b(2.f * qr) | ((u32)f2b(-2.f * qi) << 16);
      }
      *(u32x4*)&TRb[((size_t)lh * 128 + t) * 256 + 128 + 64*pass + 8*g] = v;
    }
    __syncthreads();
  }
  // T fill (x4 = 8 j per lane)
  #pragma unroll
  for (int it = 0; it < 8; ++it) {
    int idx = it * 256 + tid;
    int t = idx >> 4, g = idx & 15;
    int j0 = 8 * g;
    u32x4 v;
    #pragma unroll
    for (int e = 0; e < 4; ++e) {
      int j = j0 + 2*e;
      u32 lo = (j     <= t) ? (u32)f2b(kts[t - j])     : 0u;
      u32 hi = (j + 1 <= t) ? (u32)f2b(kts[t - j - 1]) : 0u;
      v[e] = lo | (hi << 16);
    }
    *(u32x4*)&TRb[((size_t)lh * 128 + t) * 256 + j0] = v;
  }
}

// ---------------- W -> bf16 ----------------
__global__ __launch_bounds__(256) void cvtw_k(
    const float* __restrict__ w, __hip_bfloat16* __restrict__ wb, int n) {
  int i = blockIdx.x * 256 + threadIdx.x;
  if (i < n) wb[i] = __float2bfloat16(w[i]);
}

// ---------------- lntr: LN (over H) + transpose -> zt (h, bc, j) bf16 ----------
template <bool SRCF32>
__global__ __launch_bounds__(512) void lntr_k(
    const void* __restrict__ srcv, const float* __restrict__ sc,
    const float* __restrict__ bi, u16* __restrict__ zt) {
  int bc = blockIdx.x, jh = blockIdx.y;
  __shared__ u16 Lt[64][Hq + 6];
  int wave = threadIdx.x >> 6, lane = threadIdx.x & 63;
  float4 scv = ((const float4*)sc)[lane];
  float4 biv = ((const float4*)bi)[lane];
  #pragma unroll
  for (int rr = 0; rr < 8; ++rr) {
    int j = wave * 8 + rr;
    size_t row = (size_t)bc * LC + jh * 64 + j;
    float4 v;
    if constexpr (SRCF32) {
      v = ((const float4*)((const float*)srcv + row * Hq))[lane];
    } else {
      ushort4 u = ((const ushort4*)((const u16*)srcv + row * Hq))[lane];
      v.x = b2f(u.x); v.y = b2f(u.y); v.z = b2f(u.z); v.w = b2f(u.w);
    }
    float s  = v.x + v.y + v.z + v.w;
    float s2 = v.x*v.x + v.y*v.y + v.z*v.z + v.w*v.w;
    for (int off = 32; off; off >>= 1) { s += __shfl_down(s, off); s2 += __shfl_down(s2, off); }
    s = __shfl(s, 0); s2 = __shfl(s2, 0);
    float mu = s * (1.f / Hq);
    float var = s2 * (1.f / Hq) - mu * mu;
    float r = rsqrtf(var + 1e-5f);
    u32 w0 = (u32)f2b((v.x - mu) * r * scv.x + biv.x)
           | ((u32)f2b((v.y - mu) * r * scv.y + biv.y) << 16);
    u32 w1 = (u32)f2b((v.z - mu) * r * scv.z + biv.z)
           | ((u32)f2b((v.w - mu) * r * scv.w + biv.w) << 16);
    *(u32*)&Lt[j][4 * lane]     = w0;
    *(u32*)&Lt[j][4 * lane + 2] = w1;
  }
  __syncthreads();
  #pragma unroll
  for (int it = 0; it < 16; ++it) {
    int idx = it * 512 + threadIdx.x;   // h*32 + jl
    int h = idx >> 5, jl = idx & 31;
    u32 lo = Lt[2*jl][h], hi = Lt[2*jl+1][h];
    ((u32*)zt)[((size_t)h * BC + bc) * 64 + jh * 32 + jl] = lo | (hi << 16);
  }
}

// ---------------- s4core: MFMA + in-reg scan + MFMA, double-buffered B ----------
__global__ __launch_bounds__(512) void s4core_k(
    const u16* __restrict__ zt, const u16* __restrict__ Vb,
    const u16* __restrict__ TRb, const float* __restrict__ wLc,
    u16* __restrict__ ytb) {
  int h = blockIdx.y;
  int m0 = blockIdx.x * 128;
  __shared__ u16 As[2][128 * 64];   // zt K-halves; later prev-states
  __shared__ u16 Bs[2][128 * 64];   // double-buffered B tiles
  int tid = threadIdx.x;
  int wid = tid >> 6, lane = tid & 63;
  int cl = lane & 15, kq = lane >> 4;
  int wm = wid & 1, wn = wid >> 1;

  const u16* Ab  = zt  + ((size_t)h * BC + m0) * 128;
  const u16* Vbb = Vb  + (size_t)h * 128 * 128;
  const u16* Tbb = TRb + (size_t)h * 128 * 256;

  #pragma unroll
  for (int half = 0; half < 2; ++half)
    #pragma unroll
    for (int q = 0; q < 2; ++q) {
      int idx = q * 512 + tid;
      int r = idx >> 3, ch = idx & 7;
      gload16(Ab + (size_t)r * 128 + half * 64 + ((ch ^ (r & 7)) << 3),
              (char*)As[half] + (size_t)(q * 512 + (tid & ~63)) * 16);
    }

  auto stageB = [&](const u16* base, int stride, int col0, u16* dst) {
    #pragma unroll
    for (int q = 0; q < 2; ++q) {
      int idx = q * 512 + tid;
      int r = idx >> 3, ch = idx & 7;
      gload16(base + (size_t)r * stride + col0 + ((ch ^ (r & 7)) << 3),
              (char*)dst + (size_t)(q * 512 + (tid & ~63)) * 16);
    }
  };

  f32x4 accS[4][2] = {};
  f32x4 accY[4][2] = {};

  auto mfstep = [&](const u16* Asrc, const u16* Bsrc, f32x4 (*acc)[2]) {
    #pragma unroll
    for (int kk = 0; kk < 2; ++kk) {
      short8 a[4], bf[2];
      #pragma unroll
      for (int mi = 0; mi < 4; ++mi) {
        int m = wm * 64 + mi * 16 + cl;
        int ch = (kk * 4 + kq) ^ (m & 7);
        a[mi] = *(const short8*)(Asrc + m * 64 + ch * 8);
      }
      #pragma unroll
      for (int ni = 0; ni < 2; ++ni) {
        int n = wn * 32 + ni * 16 + cl;
        int ch = (kk * 4 + kq) ^ (n & 7);
        bf[ni] = *(const short8*)(Bsrc + n * 64 + ch * 8);
      }
      #pragma unroll
      for (int mi = 0; mi < 4; ++mi)
        #pragma unroll
        for (int ni = 0; ni < 2; ++ni)
          acc[mi][ni] = __builtin_amdgcn_mfma_f32_16x16x32_bf16(
              a[mi], bf[ni], acc[mi][ni], 0, 0, 0);
    }
  };

  stageB(Vbb, 128, 0, Bs[0]);
  __syncthreads();                                               // S1
  stageB(Vbb, 128, 64, Bs[1]);
  mfstep(As[0], Bs[0], accS);  __syncthreads();                  // S2
  stageB(Tbb, 256, 0, Bs[0]);
  mfstep(As[1], Bs[1], accS);  __syncthreads();                  // S3
  stageB(Tbb, 256, 64, Bs[1]);
  mfstep(As[0], Bs[0], accY);  __syncthreads();                  // S4
  stageB(Tbb, 256, 128, Bs[0]);
  mfstep(As[1], Bs[1], accY);  __syncthreads();                  // S5

  // ---- in-register scan over c; accS becomes prev-state ----
  float sgn = (cl & 1) ? 1.f : -1.f;
  #pragma unroll
  for (int ni = 0; ni < 2; ++ni) {
    int n = (wn * 32 + ni * 16 + cl) >> 1;
    float wr = wLc[2 * (h * Nst + n)];
    float wi = wLc[2 * (h * Nst + n) + 1];
    float swi = sgn * wi;
    #pragma unroll
    for (int mi = 0; mi < 4; ++mi) {
      float carry = 0.f;
      #pragma unroll
      for (int c = 0; c < NC; ++c) {
        float part = __shfl_xor(carry, 1);
        float a_used = accS[mi][ni][c & 3];
        float Sc = fmaf(wr, carry, fmaf(swi, part, a_used));
        if (kq == (c >> 2)) accS[mi][ni][c & 3] = carry;   // prev-state
        carry = __shfl(Sc, ((c >> 2) << 4) + cl);
      }
    }
  }

  #pragma unroll
  for (int mi = 0; mi < 4; ++mi)
    #pragma unroll
    for (int ni = 0; ni < 2; ++ni) {
      int colv = wn * 32 + ni * 16 + cl;
      int half = colv >> 6, cv = colv & 63;
      #pragma unroll
      for (int r = 0; r < 4; ++r) {
        int m = wm * 64 + mi * 16 + kq * 4 + r;
        As[half][m * 64 + (((cv >> 3) ^ (m & 7)) << 3) + (cv & 7)] =
            f2b(accS[mi][ni][r]);
      }
    }
  stageB(Tbb, 256, 192, Bs[1]);
  __syncthreads();                                               // S6
  mfstep(As[0], Bs[0], accY);     // T128 x prev-state lo
  mfstep(As[1], Bs[1], accY);     // T192 x prev-state hi

  #pragma unroll
  for (int mi = 0; mi < 4; ++mi)
    #pragma unroll
    for (int ni = 0; ni < 2; ++ni) {
      int t = wn * 32 + ni * 16 + cl;
      #pragma unroll
      for (int r = 0; r < 4; ++r) {
        int row = m0 + wm * 64 + mi * 16 + kq * 4 + r;
        float x = accY[mi][ni][r];
        float inner = 0.7978845608028654f * fmaf(0.044715f, x*x*x, x);
        float g = 0.5f * x * (1.f + tanhf(inner));
        ytb[((size_t)h * BC + row) * LC + t] = f2b(g);
      }
    }
}

// ---------------- gemm: A from ytb via in-LDS transpose + bias/GLU/residual ----
// SRCF32: residual source is f32 (layer 0: x); else bf16 hbf.
// DSTF32: write f32 (layer 3: d_out); else bf16 hbf.
template <bool SRCF32, bool DSTF32>
__global__ __launch_bounds__(256) void gemm_k(
    const u16* __restrict__ ytb, const __hip_bfloat16* __restrict__ Wb,
    const float* __restrict__ bout, const void* __restrict__ rsrcv,
    void* __restrict__ dstv) {
  __shared__ u32 Lt32[64 * 65];             // [hh][tp], stride 65
  __shared__ __hip_bfloat16 As[128 * 64];
  __shared__ __hip_bfloat16 Bs[128 * 64];
  int tid = threadIdx.x;
  int bc = blockIdx.x;
  int m0 = bc * 128;
  int ot = blockIdx.y;
  int wid = tid >> 6, lane = tid & 63;
  int cl = lane & 15, kq = lane >> 4;
  f32x4 acc[2][8] = {};
  for (int kt = 0; kt < GK / 64; ++kt) {
    int k0 = kt * 64;
    // B staging (async)
    #pragma unroll
    for (int q = 0; q < 4; ++q) {
      int idx = q * 256 + tid;
      int r = idx >> 3, ch = idx & 7;
      int wrow = ot * 64 + r + ((r >= 64) ? 192 : 0);
      const __hip_bfloat16* sB =
          Wb + (size_t)wrow * GK + k0 + ((ch ^ (r & 7)) << 3);
      gload16(sB, (char*)Bs + (size_t)(q * 256 + (tid & ~63)) * 16);
    }
    // Lt32 fill: row hh of ytb (h=k0+hh), 64 u32 t-pairs, coalesced
    #pragma unroll
    for (int i2 = 0; i2 < 16; ++i2) {
      int idx = i2 * 256 + tid;
      int hh = idx >> 6, tp = idx & 63;
      Lt32[hh * 65 + tp] =
          ((const u32*)ytb)[((size_t)(k0 + hh) * BC + bc) * 64 + tp];
    }
    __syncthreads();
    // As write: element (m=t, k=2hl / 2hl+1) packed u32, swizzled layout
    #pragma unroll
    for (int i2 = 0; i2 < 16; ++i2) {
      int idx = i2 * 256 + tid;
      int m = idx >> 5, hl = idx & 31;
      u32 v0 = Lt32[(2 * hl) * 65 + (m >> 1)];
      u32 v1 = Lt32[(2 * hl + 1) * 65 + (m >> 1)];
      u32 lo = (m & 1) ? (v0 >> 16) : (v0 & 0xffffu);
      u32 hi = (m & 1) ? (v1 >> 16) : (v1 & 0xffffu);
      ((u32*)As)[m * 32 + (((hl >> 2) ^ (m & 7)) << 2) + (hl & 3)] =
          lo | (hi << 16);
    }
    __syncthreads();
    #pragma unroll
    for (int kk = 0; kk < 2; ++kk) {
      short8 a[2], bfr[8];
      #pragma unroll
      for (int mi = 0; mi < 2; ++mi) {
        int m = wid * 32 + mi * 16 + cl;
        int ch = (kk * 4 + kq) ^ (m & 7);
        a[mi] = *(const short8*)(As + m * 64 + ch * 8);
      }
      #pragma unroll
      for (int ni = 0; ni < 8; ++ni) {
        int n = ni * 16 + cl;
        int ch = (kk * 4 + kq) ^ (n & 7);
        bfr[ni] = *(const short8*)(Bs + n * 64 + ch * 8);
      }
      #pragma unroll
      for (int mi = 0; mi < 2; ++mi)
        #pragma unroll
        for (int ni = 0; ni < 8; ++ni)
          acc[mi][ni] = __builtin_amdgcn_mfma_f32_16x16x32_bf16(
              a[mi], bfr[ni], acc[mi][ni], 0, 0, 0);
    }
    __syncthreads();
  }
  #pragma unroll
  for (int mi = 0; mi < 2; ++mi) {
    #pragma unroll
    for (int ni = 0; ni < 4; ++ni) {
      int o1 = ot * 64 + ni * 16 + cl;
      float b1 = bout[o1], b2 = bout[o1 + 256];
      #pragma unroll
      for (int r = 0; r < 4; ++r) {
        int row = m0 + wid * 32 + mi * 16 + kq * 4 + r;
        float z1 = acc[mi][ni][r] + b1;
        float z2 = acc[mi][ni + 4][r] + b2;
        float g = z1 / (1.f + expf(-z2));
        size_t idx = (size_t)row * Hq + o1;
        float rv;
        if constexpr (SRCF32) rv = ((const float*)rsrcv)[idx];
        else                  rv = b2f(((const u16*)rsrcv)[idx]);
        float o = rv + g;
        if constexpr (DSTF32) ((float*)dstv)[idx] = o;
        else                  ((u16*)dstv)[idx] = f2b(o);
      }
    }
  }
}

extern "C" void kernel_launch(void* const* d_in, const int* in_sizes, int n_in,
                              void* d_out, int out_size, void* d_ws, size_t ws_size,
                              hipStream_t stream) {
  (void)in_sizes; (void)n_in; (void)out_size; (void)ws_size;
  const float* x      = (const float*)d_in[0];
  const float* log_dt = (const float*)d_in[1];
  const float* Alog   = (const float*)d_in[2];
  const float* Aim    = (const float*)d_in[3];
  const float* Cre    = (const float*)d_in[4];
  const float* Cim    = (const float*)d_in[5];
  const float* Dv     = (const float*)d_in[6];
  const float* Wout   = (const float*)d_in[7];
  const float* bout   = (const float*)d_in[8];
  const float* lns    = (const float*)d_in[9];
  const float* lnb    = (const float*)d_in[10];

  float* hb = (float*)d_out;
  float* p  = (float*)d_ws;
  u16* zt  = (u16*)p; p += SZ/2;               // (h, bc, j) bf16
  u16* ytb = (u16*)p; p += SZ/2;               // (h, bc, t) bf16
  u16* hbf = (u16*)p; p += SZ/2;               // bf16 residual stream
  u16* Vb  = (u16*)p; p += SZ;                 // NL*Hq*128*128 u16
  u16* TRb = (u16*)p; p += 2*SZ;               // NL*Hq*128*256 u16
  u16* Wb  = (u16*)p; p += (NL*2*Hq*Hq)/2;     // bf16 weights, all layers
  float* wLc = p;  p += NL*2*Hq*Nst;

  cvtw_k<<<(NL*2*Hq*Hq)/256, 256, 0, stream>>>(Wout, (__hip_bfloat16*)Wb, NL*2*Hq*Hq);
  param_k<<<NL*Hq, 256, 0, stream>>>(log_dt, Alog, Aim, Cre, Cim, Dv, Vb, TRb, wLc);

  for (int i = 0; i < NL; ++i) {
    if (i == 0)
      lntr_k<true><<<dim3(BC, 2), 512, 0, stream>>>(x, lns + i*Hq, lnb + i*Hq, zt);
    else
      lntr_k<false><<<dim3(BC, 2), 512, 0, stream>>>(hbf, lns + i*Hq, lnb + i*Hq, zt);

    s4core_k<<<dim3(2, Hq), 512, 0, stream>>>(
        zt, Vb + (size_t)i * Hq * 128 * 128, TRb + (size_t)i * Hq * 128 * 256,
        wLc + (size_t)i * 2 * Hq * Nst, ytb);

    const __hip_bfloat16* Wbi = (const __hip_bfloat16*)(Wb + (size_t)i * 2 * Hq * Hq);
    const float* bo = bout + (size_t)i * 2 * Hq;
    if (i == 0)
      gemm_k<true, false><<<dim3(BC, 4), 256, 0, stream>>>(ytb, Wbi, bo, x, hbf);
    else if (i == NL - 1)
      gemm_k<false, true><<<dim3(BC, 4), 256, 0, stream>>>(ytb, Wbi, bo, hbf, hb);
    else
      gemm_k<false, false><<<dim3(BC, 4), 256, 0, stream>>>(ytb, Wbi, bo, hbf, hbf);
  }
}

// Round 16
// 300.196 us; speedup vs baseline: 1.0309x; 1.0271x over previous
//
#include <hip/hip_runtime.h>
#include <hip/hip_bf16.h>
#include <math.h>

#define Bq 16
#define Lq 2048
#define Hq 256
#define Nst 64
#define LC 128
#define NC 16
#define NL 4
#define BC 256   // Bq*NC
#define GK 256
#define PWS 140  // pw row stride: 140*4 % 16 == 0 (b128-aligned rows); 140%32=12
#define SZ ((size_t)Bq * Lq * Hq)   // 8388608

typedef __attribute__((ext_vector_type(8))) short short8;
typedef __attribute__((ext_vector_type(4))) float f32x4;
typedef __attribute__((ext_vector_type(4))) unsigned int u32x4;
typedef unsigned short u16;
typedef unsigned int u32;

__device__ __forceinline__ u16 f2b(float x) {
  __hip_bfloat16 b = __float2bfloat16(x);
  u16 u; __builtin_memcpy(&u, &b, 2); return u;
}
__device__ __forceinline__ float b2f(u16 u) {
  u32 t = ((u32)u) << 16; float f; __builtin_memcpy(&f, &t, 4); return f;
}
__device__ __forceinline__ void gload16(const void* g, void* l) {
  __builtin_amdgcn_global_load_lds(
      (const __attribute__((address_space(1))) void*)g,
      (__attribute__((address_space(3))) void*)l, 16, 0, 0);
}

// ---------------- param_k: one block per (layer,h) = lh ----------------
// pw rows 16B-aligned (PWS=140) -> V fill gathers via 2x ds_read_b128.
// Tail: converts this block's 512-element W slice (absorbs cvtw_k).
__global__ __launch_bounds__(256) void param_k(
    const float* __restrict__ log_dt, const float* __restrict__ Alog,
    const float* __restrict__ Aim, const float* __restrict__ Cre,
    const float* __restrict__ Cim, const float* __restrict__ Dv,
    const float* __restrict__ Wout,
    u16* __restrict__ Vb, u16* __restrict__ TRb, float* __restrict__ wLc,
    u16* __restrict__ Wb) {
  int lh = blockIdx.x;
  int tid = threadIdx.x;
  __shared__ alignas(16) float pwre[32][PWS];
  __shared__ alignas(16) float pwim[32][PWS];
  __shared__ float cdre[32], cdim[32];
  __shared__ float kacc[LC];
  __shared__ float kts[LC];
  int ln2 = tid & 31, pg = tid >> 5;   // n-in-half, power segment 0..7
  float dlt = expf(log_dt[lh]);

  for (int pass = 0; pass < 2; ++pass) {
    int n = pass * 32 + ln2;
    int gi = lh * Nst + n;
    float ar = -expf(Alog[gi]);
    float ai = Aim[gi];
    float dr = ar * dlt, di = ai * dlt;
    float er = expf(dr); float sn, cs; sincosf(di, &sn, &cs);
    float wr = er * cs, wi = er * sn;                 // w
    float p0 = (float)(16 * pg);
    float eb = expf(dr * p0); float sb, cb; sincosf(di * p0, &sb, &cb);
    float pr = eb * cb, pi = eb * sb;                 // w^(16*pg)
    #pragma unroll
    for (int s = 0; s < 16; ++s) {
      pwre[ln2][16*pg + s] = pr; pwim[ln2][16*pg + s] = pi;
      float t = pr*wr - pi*wi; pi = fmaf(pr, wi, pi*wr); pr = t;
    }
    if (pg == 7) {                                    // p = 128
      pwre[ln2][128] = pr; pwim[ln2][128] = pi;
      wLc[2*gi] = pr; wLc[2*gi+1] = pi;
    }
    if (pg == 0) {                                    // Cd = C*(w-1)/A
      float nr = wr - 1.f, ni = wi;
      float d2 = ar*ar + ai*ai;
      float qr = (nr*ar + ni*ai) / d2;
      float qi = (ni*ar - nr*ai) / d2;
      float cr = Cre[gi], ci = Cim[gi];
      cdre[ln2] = cr*qr - ci*qi;
      cdim[ln2] = cr*qi + ci*qr;
    }
    __syncthreads();
    // kts partial over this n-half
    if (tid < LC) {
      float s = 0.f;
      #pragma unroll
      for (int k = 0; k < 32; ++k)
        s = fmaf(cdre[k], pwre[k][tid], fmaf(-cdim[k], pwim[k][tid], s));
      if (pass == 0) kacc[tid] = s;
      else kts[tid] = 2.f * (kacc[tid] + s) + ((tid == 0) ? Dv[lh] : 0.f);
    }
    // V fill (x4 = 8 j per lane): two b128 LDS reads instead of 8 scalars
    #pragma unroll
    for (int it = 0; it < 4; ++it) {
      int idx = it * 256 + tid;
      int rl = idx >> 4, g = idx & 15;
      int nl = rl >> 1, im = rl & 1;
      const float* row = im ? pwim[nl] : pwre[nl];
      int pj = 127 - 8 * g;
      float4 lo4 = *(const float4*)&row[pj - 7];   // row[pj-7..pj-4]
      float4 hi4 = *(const float4*)&row[pj - 3];   // row[pj-3..pj]
      u32x4 v;
      v[0] = (u32)f2b(hi4.w) | ((u32)f2b(hi4.z) << 16);   // j=8g,8g+1
      v[1] = (u32)f2b(hi4.y) | ((u32)f2b(hi4.x) << 16);   // j=8g+2,8g+3
      v[2] = (u32)f2b(lo4.w) | ((u32)f2b(lo4.z) << 16);   // j=8g+4,8g+5
      v[3] = (u32)f2b(lo4.y) | ((u32)f2b(lo4.x) << 16);   // j=8g+6,8g+7
      *(u32x4*)&Vb[((size_t)lh * 128 + 64*pass + rl) * 128 + 8*g] = v;
    }
    // R fill (x4 = 8 rr per lane)
    #pragma unroll
    for (int it = 0; it < 4; ++it) {
      int idx = it * 256 + tid;
      int t = idx >> 3, g = idx & 7;
      u32x4 v;
      #pragma unroll
      for (int k = 0; k < 4; ++k) {
        int nl = 4*g + k;
        float wpr = pwre[nl][t+1], wpi = pwim[nl][t+1];
        float qr = cdre[nl]*wpr - cdim[nl]*wpi;
        float qi = cdre[nl]*wpi + cdim[nl]*wpr;
        v[k] = (u32)f2b(2.f * qr) | ((u32)f2b(-2.f * qi) << 16);
      }
      *(u32x4*)&TRb[((size_t)lh * 128 + t) * 256 + 128 + 64*pass + 8*g] = v;
    }
    __syncthreads();   // fills done before table overwritten / kts final
  }
  // T fill (x4 = 8 j per lane)
  #pragma unroll
  for (int it = 0; it < 8; ++it) {
    int idx = it * 256 + tid;
    int t = idx >> 4, g = idx & 15;
    int j0 = 8 * g;
    u32x4 v;
    #pragma unroll
    for (int e = 0; e < 4; ++e) {
      int j = j0 + 2*e;
      u32 lo = (j     <= t) ? (u32)f2b(kts[t - j])     : 0u;
      u32 hi = (j + 1 <= t) ? (u32)f2b(kts[t - j - 1]) : 0u;
      v[e] = lo | (hi << 16);
    }
    *(u32x4*)&TRb[((size_t)lh * 128 + t) * 256 + j0] = v;
  }
  // W convert tail (absorbed cvtw_k): this block's 512 consecutive elements
  {
    float2 w2 = ((const float2*)(Wout + (size_t)lh * 512))[tid];
    ((u32*)Wb)[(size_t)lh * 256 + tid] =
        (u32)f2b(w2.x) | ((u32)f2b(w2.y) << 16);
  }
}

// ---------------- lntr: LN (over H) + transpose -> zt (h, bc, j) bf16 ----------
template <bool SRCF32>
__global__ __launch_bounds__(512) void lntr_k(
    const void* __restrict__ srcv, const float* __restrict__ sc,
    const float* __restrict__ bi, u16* __restrict__ zt) {
  int bc = blockIdx.x, jh = blockIdx.y;
  __shared__ u16 Lt[64][Hq + 6];
  int wave = threadIdx.x >> 6, lane = threadIdx.x & 63;
  float4 scv = ((const float4*)sc)[lane];
  float4 biv = ((const float4*)bi)[lane];
  #pragma unroll
  for (int rr = 0; rr < 8; ++rr) {
    int j = wave * 8 + rr;
    size_t row = (size_t)bc * LC + jh * 64 + j;
    float4 v;
    if constexpr (SRCF32) {
      v = ((const float4*)((const float*)srcv + row * Hq))[lane];
    } else {
      ushort4 u = ((const ushort4*)((const u16*)srcv + row * Hq))[lane];
      v.x = b2f(u.x); v.y = b2f(u.y); v.z = b2f(u.z); v.w = b2f(u.w);
    }
    float s  = v.x + v.y + v.z + v.w;
    float s2 = v.x*v.x + v.y*v.y + v.z*v.z + v.w*v.w;
    for (int off = 32; off; off >>= 1) { s += __shfl_down(s, off); s2 += __shfl_down(s2, off); }
    s = __shfl(s, 0); s2 = __shfl(s2, 0);
    float mu = s * (1.f / Hq);
    float var = s2 * (1.f / Hq) - mu * mu;
    float r = rsqrtf(var + 1e-5f);
    u32 w0 = (u32)f2b((v.x - mu) * r * scv.x + biv.x)
           | ((u32)f2b((v.y - mu) * r * scv.y + biv.y) << 16);
    u32 w1 = (u32)f2b((v.z - mu) * r * scv.z + biv.z)
           | ((u32)f2b((v.w - mu) * r * scv.w + biv.w) << 16);
    *(u32*)&Lt[j][4 * lane]     = w0;
    *(u32*)&Lt[j][4 * lane + 2] = w1;
  }
  __syncthreads();
  #pragma unroll
  for (int it = 0; it < 16; ++it) {
    int idx = it * 512 + threadIdx.x;   // h*32 + jl
    int h = idx >> 5, jl = idx & 31;
    u32 lo = Lt[2*jl][h], hi = Lt[2*jl+1][h];
    ((u32*)zt)[((size_t)h * BC + bc) * 64 + jh * 32 + jl] = lo | (hi << 16);
  }
}

// ---------------- s4core: MFMA + in-reg scan + MFMA, double-buffered B ----------
__global__ __launch_bounds__(512) void s4core_k(
    const u16* __restrict__ zt, const u16* __restrict__ Vb,
    const u16* __restrict__ TRb, const float* __restrict__ wLc,
    u16* __restrict__ ytb) {
  int h = blockIdx.y;
  int m0 = blockIdx.x * 128;
  __shared__ u16 As[2][128 * 64];   // zt K-halves; later prev-states
  __shared__ u16 Bs[2][128 * 64];   // double-buffered B tiles
  int tid = threadIdx.x;
  int wid = tid >> 6, lane = tid & 63;
  int cl = lane & 15, kq = lane >> 4;
  int wm = wid & 1, wn = wid >> 1;

  const u16* Ab  = zt  + ((size_t)h * BC + m0) * 128;
  const u16* Vbb = Vb  + (size_t)h * 128 * 128;
  const u16* Tbb = TRb + (size_t)h * 128 * 256;

  #pragma unroll
  for (int half = 0; half < 2; ++half)
    #pragma unroll
    for (int q = 0; q < 2; ++q) {
      int idx = q * 512 + tid;
      int r = idx >> 3, ch = idx & 7;
      gload16(Ab + (size_t)r * 128 + half * 64 + ((ch ^ (r & 7)) << 3),
              (char*)As[half] + (size_t)(q * 512 + (tid & ~63)) * 16);
    }

  auto stageB = [&](const u16* base, int stride, int col0, u16* dst) {
    #pragma unroll
    for (int q = 0; q < 2; ++q) {
      int idx = q * 512 + tid;
      int r = idx >> 3, ch = idx & 7;
      gload16(base + (size_t)r * stride + col0 + ((ch ^ (r & 7)) << 3),
              (char*)dst + (size_t)(q * 512 + (tid & ~63)) * 16);
    }
  };

  f32x4 accS[4][2] = {};
  f32x4 accY[4][2] = {};

  auto mfstep = [&](const u16* Asrc, const u16* Bsrc, f32x4 (*acc)[2]) {
    #pragma unroll
    for (int kk = 0; kk < 2; ++kk) {
      short8 a[4], bf[2];
      #pragma unroll
      for (int mi = 0; mi < 4; ++mi) {
        int m = wm * 64 + mi * 16 + cl;
        int ch = (kk * 4 + kq) ^ (m & 7);
        a[mi] = *(const short8*)(Asrc + m * 64 + ch * 8);
      }
      #pragma unroll
      for (int ni = 0; ni < 2; ++ni) {
        int n = wn * 32 + ni * 16 + cl;
        int ch = (kk * 4 + kq) ^ (n & 7);
        bf[ni] = *(const short8*)(Bsrc + n * 64 + ch * 8);
      }
      #pragma unroll
      for (int mi = 0; mi < 4; ++mi)
        #pragma unroll
        for (int ni = 0; ni < 2; ++ni)
          acc[mi][ni] = __builtin_amdgcn_mfma_f32_16x16x32_bf16(
              a[mi], bf[ni], acc[mi][ni], 0, 0, 0);
    }
  };

  stageB(Vbb, 128, 0, Bs[0]);
  __syncthreads();                                               // S1
  stageB(Vbb, 128, 64, Bs[1]);
  mfstep(As[0], Bs[0], accS);  __syncthreads();                  // S2
  stageB(Tbb, 256, 0, Bs[0]);
  mfstep(As[1], Bs[1], accS);  __syncthreads();                  // S3
  stageB(Tbb, 256, 64, Bs[1]);
  mfstep(As[0], Bs[0], accY);  __syncthreads();                  // S4
  stageB(Tbb, 256, 128, Bs[0]);
  mfstep(As[1], Bs[1], accY);  __syncthreads();                  // S5

  // ---- in-register scan over c; accS becomes prev-state ----
  float sgn = (cl & 1) ? 1.f : -1.f;
  #pragma unroll
  for (int ni = 0; ni < 2; ++ni) {
    int n = (wn * 32 + ni * 16 + cl) >> 1;
    float wr = wLc[2 * (h * Nst + n)];
    float wi = wLc[2 * (h * Nst + n) + 1];
    float swi = sgn * wi;
    #pragma unroll
    for (int mi = 0; mi < 4; ++mi) {
      float carry = 0.f;
      #pragma unroll
      for (int c = 0; c < NC; ++c) {
        float part = __shfl_xor(carry, 1);
        float a_used = accS[mi][ni][c & 3];
        float Sc = fmaf(wr, carry, fmaf(swi, part, a_used));
        if (kq == (c >> 2)) accS[mi][ni][c & 3] = carry;   // prev-state
        carry = __shfl(Sc, ((c >> 2) << 4) + cl);
      }
    }
  }

  #pragma unroll
  for (int mi = 0; mi < 4; ++mi)
    #pragma unroll
    for (int ni = 0; ni < 2; ++ni) {
      int colv = wn * 32 + ni * 16 + cl;
      int half = colv >> 6, cv = colv & 63;
      #pragma unroll
      for (int r = 0; r < 4; ++r) {
        int m = wm * 64 + mi * 16 + kq * 4 + r;
        As[half][m * 64 + (((cv >> 3) ^ (m & 7)) << 3) + (cv & 7)] =
            f2b(accS[mi][ni][r]);
      }
    }
  stageB(Tbb, 256, 192, Bs[1]);
  __syncthreads();                                               // S6
  mfstep(As[0], Bs[0], accY);     // T128 x prev-state lo
  mfstep(As[1], Bs[1], accY);     // T192 x prev-state hi

  #pragma unroll
  for (int mi = 0; mi < 4; ++mi)
    #pragma unroll
    for (int ni = 0; ni < 2; ++ni) {
      int t = wn * 32 + ni * 16 + cl;
      #pragma unroll
      for (int r = 0; r < 4; ++r) {
        int row = m0 + wm * 64 + mi * 16 + kq * 4 + r;
        float x = accY[mi][ni][r];
        float inner = 0.7978845608028654f * fmaf(0.044715f, x*x*x, x);
        float g = 0.5f * x * (1.f + tanhf(inner));
        ytb[((size_t)h * BC + row) * LC + t] = f2b(g);
      }
    }
}

// ---------------- gemm: A from ytb via in-LDS transpose + bias/GLU/residual ----
// SRCF32: residual source is f32 (layer 0: x); else bf16 hbf.
// DSTF32: write f32 (layer 3: d_out); else bf16 hbf.
template <bool SRCF32, bool DSTF32>
__global__ __launch_bounds__(256) void gemm_k(
    const u16* __restrict__ ytb, const __hip_bfloat16* __restrict__ Wb,
    const float* __restrict__ bout, const void* __restrict__ rsrcv,
    void* __restrict__ dstv) {
  __shared__ u32 Lt32[64 * 65];             // [hh][tp], stride 65
  __shared__ __hip_bfloat16 As[128 * 64];
  __shared__ __hip_bfloat16 Bs[128 * 64];
  int tid = threadIdx.x;
  int bc = blockIdx.x;
  int m0 = bc * 128;
  int ot = blockIdx.y;
  int wid = tid >> 6, lane = tid & 63;
  int cl = lane & 15, kq = lane >> 4;
  f32x4 acc[2][8] = {};
  for (int kt = 0; kt < GK / 64; ++kt) {
    int k0 = kt * 64;
    // B staging (async)
    #pragma unroll
    for (int q = 0; q < 4; ++q) {
      int idx = q * 256 + tid;
      int r = idx >> 3, ch = idx & 7;
      int wrow = ot * 64 + r + ((r >= 64) ? 192 : 0);
      const __hip_bfloat16* sB =
          Wb + (size_t)wrow * GK + k0 + ((ch ^ (r & 7)) << 3);
      gload16(sB, (char*)Bs + (size_t)(q * 256 + (tid & ~63)) * 16);
    }
    // Lt32 fill: row hh of ytb (h=k0+hh), 64 u32 t-pairs, coalesced
    #pragma unroll
    for (int i2 = 0; i2 < 16; ++i2) {
      int idx = i2 * 256 + tid;
      int hh = idx >> 6, tp = idx & 63;
      Lt32[hh * 65 + tp] =
          ((const u32*)ytb)[((size_t)(k0 + hh) * BC + bc) * 64 + tp];
    }
    __syncthreads();
    // As write: element (m=t, k=2hl / 2hl+1) packed u32, swizzled layout
    #pragma unroll
    for (int i2 = 0; i2 < 16; ++i2) {
      int idx = i2 * 256 + tid;
      int m = idx >> 5, hl = idx & 31;
      u32 v0 = Lt32[(2 * hl) * 65 + (m >> 1)];
      u32 v1 = Lt32[(2 * hl + 1) * 65 + (m >> 1)];
      u32 lo = (m & 1) ? (v0 >> 16) : (v0 & 0xffffu);
      u32 hi = (m & 1) ? (v1 >> 16) : (v1 & 0xffffu);
      ((u32*)As)[m * 32 + (((hl >> 2) ^ (m & 7)) << 2) + (hl & 3)] =
          lo | (hi << 16);
    }
    __syncthreads();
    #pragma unroll
    for (int kk = 0; kk < 2; ++kk) {
      short8 a[2], bfr[8];
      #pragma unroll
      for (int mi = 0; mi < 2; ++mi) {
        int m = wid * 32 + mi * 16 + cl;
        int ch = (kk * 4 + kq) ^ (m & 7);
        a[mi] = *(const short8*)(As + m * 64 + ch * 8);
      }
      #pragma unroll
      for (int ni = 0; ni < 8; ++ni) {
        int n = ni * 16 + cl;
        int ch = (kk * 4 + kq) ^ (n & 7);
        bfr[ni] = *(const short8*)(Bs + n * 64 + ch * 8);
      }
      #pragma unroll
      for (int mi = 0; mi < 2; ++mi)
        #pragma unroll
        for (int ni = 0; ni < 8; ++ni)
          acc[mi][ni] = __builtin_amdgcn_mfma_f32_16x16x32_bf16(
              a[mi], bfr[ni], acc[mi][ni], 0, 0, 0);
    }
    __syncthreads();
  }
  #pragma unroll
  for (int mi = 0; mi < 2; ++mi) {
    #pragma unroll
    for (int ni = 0; ni < 4; ++ni) {
      int o1 = ot * 64 + ni * 16 + cl;
      float b1 = bout[o1], b2 = bout[o1 + 256];
      #pragma unroll
      for (int r = 0; r < 4; ++r) {
        int row = m0 + wid * 32 + mi * 16 + kq * 4 + r;
        float z1 = acc[mi][ni][r] + b1;
        float z2 = acc[mi][ni + 4][r] + b2;
        float g = z1 / (1.f + expf(-z2));
        size_t idx = (size_t)row * Hq + o1;
        float rv;
        if constexpr (SRCF32) rv = ((const float*)rsrcv)[idx];
        else                  rv = b2f(((const u16*)rsrcv)[idx]);
        float o = rv + g;
        if constexpr (DSTF32) ((float*)dstv)[idx] = o;
        else                  ((u16*)dstv)[idx] = f2b(o);
      }
    }
  }
}

extern "C" void kernel_launch(void* const* d_in, const int* in_sizes, int n_in,
                              void* d_out, int out_size, void* d_ws, size_t ws_size,
                              hipStream_t stream) {
  (void)in_sizes; (void)n_in; (void)out_size; (void)ws_size;
  const float* x      = (const float*)d_in[0];
  const float* log_dt = (const float*)d_in[1];
  const float* Alog   = (const float*)d_in[2];
  const float* Aim    = (const float*)d_in[3];
  const float* Cre    = (const float*)d_in[4];
  const float* Cim    = (const float*)d_in[5];
  const float* Dv     = (const float*)d_in[6];
  const float* Wout   = (const float*)d_in[7];
  const float* bout   = (const float*)d_in[8];
  const float* lns    = (const float*)d_in[9];
  const float* lnb    = (const float*)d_in[10];

  float* hb = (float*)d_out;
  float* p  = (float*)d_ws;
  u16* zt  = (u16*)p; p += SZ/2;               // (h, bc, j) bf16
  u16* ytb = (u16*)p; p += SZ/2;               // (h, bc, t) bf16
  u16* hbf = (u16*)p; p += SZ/2;               // bf16 residual stream
  u16* Vb  = (u16*)p; p += SZ;                 // NL*Hq*128*128 u16
  u16* TRb = (u16*)p; p += 2*SZ;               // NL*Hq*128*256 u16
  u16* Wb  = (u16*)p; p += (NL*2*Hq*Hq)/2;     // bf16 weights, all layers
  float* wLc = p;  p += NL*2*Hq*Nst;

  // single param kernel (includes W conversion)
  param_k<<<NL*Hq, 256, 0, stream>>>(
      log_dt, Alog, Aim, Cre, Cim, Dv, Wout, Vb, TRb, wLc, Wb);

  for (int i = 0; i < NL; ++i) {
    if (i == 0)
      lntr_k<true><<<dim3(BC, 2), 512, 0, stream>>>(x, lns + i*Hq, lnb + i*Hq, zt);
    else
      lntr_k<false><<<dim3(BC, 2), 512, 0, stream>>>(hbf, lns + i*Hq, lnb + i*Hq, zt);

    s4core_k<<<dim3(2, Hq), 512, 0, stream>>>(
        zt, Vb + (size_t)i * Hq * 128 * 128, TRb + (size_t)i * Hq * 128 * 256,
        wLc + (size_t)i * 2 * Hq * Nst, ytb);

    const __hip_bfloat16* Wbi = (const __hip_bfloat16*)(Wb + (size_t)i * 2 * Hq * Hq);
    const float* bo = bout + (size_t)i * 2 * Hq;
    if (i == 0)
      gemm_k<true, false><<<dim3(BC, 4), 256, 0, stream>>>(ytb, Wbi, bo, x, hbf);
    else if (i == NL - 1)
      gemm_k<false, true><<<dim3(BC, 4), 256, 0, stream>>>(ytb, Wbi, bo, hbf, hb);
    else
      gemm_k<false, false><<<dim3(BC, 4), 256, 0, stream>>>(ytb, Wbi, bo, hbf, hbf);
  }
}